// Round 1
// baseline (592.989 us; speedup 1.0000x reference)
//
#include <hip/hip_runtime.h>
#include <math.h>

// Problem constants
#define BB 16
#define CE 1024
#define TT 2048
#define KK 4096
#define CC 64

// d_out offsets (floats), outputs concatenated in reference return order:
// codes (B,T) | quantized (B,CE,T) | codebook_loss | commit_loss | x_proj (B,CC,T) | quantized_proj (B,CC,T)
#define O_CODES 0
#define O_QUANT 32768
#define O_CBL   33587200
#define O_CML   33587201
#define O_XPROJ 33587202
#define O_QPROJ 35684354

// workspace offsets (floats)
#define W_WINT  0          // W_in transposed  [i=1024][o=64]
#define W_WOUTT 65536      // W_out transposed [c=64][o=1024]
#define W_CBT   131072     // cb_n transposed  [c=64][k=4096]
#define W_CBSQ  393216     // sum(cb_n^2) per k [4096]
#define W_CODES 397312     // int codes [32768]
#define W_LOSS  430080     // float accumulator

// ---------------------------------------------------------------------------
// Kernel 1: weight-norm W_in, W_out; l2-normalize codebook; zero loss accum.
// grid = 64 + 1024 + 4096 blocks of 64 threads (one wave per row).
// ---------------------------------------------------------------------------
__global__ __launch_bounds__(64) void prep_kernel(
    const float* __restrict__ v_in, const float* __restrict__ g_in,
    const float* __restrict__ v_out, const float* __restrict__ g_out,
    const float* __restrict__ cb, float* __restrict__ ws) {
  int bid = blockIdx.x, tid = threadIdx.x;
  if (bid == 0 && tid == 0) ws[W_LOSS] = 0.f;
  if (bid < 64) {
    // W_in row o: ||v_in[o,:]|| over 1024, W = (g*v)/norm, store transposed [i][o]
    int o = bid;
    float s = 0.f;
    for (int i = tid; i < CE; i += 64) { float v = v_in[o * CE + i]; s += v * v; }
    for (int off = 32; off; off >>= 1) s += __shfl_down(s, off);
    s = __shfl(s, 0);
    float norm = sqrtf(s);
    float g = g_in[o];
    for (int i = tid; i < CE; i += 64) {
      float w = (g * v_in[o * CE + i]) / norm;
      ws[W_WINT + i * 64 + o] = w;
    }
  } else if (bid < 64 + CE) {
    // W_out row o: ||v_out[o,:]|| over 64, store transposed [c][o]
    int o = bid - 64;
    float v = v_out[o * CC + tid];
    float s = v * v;
    for (int off = 32; off; off >>= 1) s += __shfl_down(s, off);
    s = __shfl(s, 0);
    float norm = sqrtf(s);
    float w = (g_out[o] * v) / norm;
    ws[W_WOUTT + tid * CE + o] = w;
  } else {
    // codebook row k: l2-normalize with eps, store transposed [c][k]; cbsq[k]
    int k = bid - 64 - CE;
    float v = cb[k * CC + tid];
    float s = v * v;
    for (int off = 32; off; off >>= 1) s += __shfl_down(s, off);
    s = __shfl(s, 0);
    float n = fmaxf(sqrtf(s), 1e-12f);
    float cn = v / n;
    ws[W_CBT + tid * KK + k] = cn;
    float s2 = cn * cn;
    for (int off = 32; off; off >>= 1) s2 += __shfl_down(s2, off);
    if (tid == 0) ws[W_CBSQ + k] = s2;
  }
}

// ---------------------------------------------------------------------------
// Kernel 2: x_proj[b,o,t] = sum_i W_in[o,i] * x[b,i,t]
// grid = 512 (b*32 + t-tile of 64), block = 256 (tx=16 x ty=16), 4x4 micro.
// ---------------------------------------------------------------------------
__global__ __launch_bounds__(256) void proj_in_kernel(
    const float* __restrict__ x, const float* __restrict__ ws,
    float* __restrict__ out) {
  __shared__ float xs[64 * 64];    // [ii][t]
  __shared__ float wls[64 * 64];   // [ii][o]
  int bid = blockIdx.x;
  int b = bid >> 5, t0 = (bid & 31) * 64;
  int tid = threadIdx.x;
  int tx = tid & 15, ty = tid >> 4;
  const float* winT = ws + W_WINT;
  float acc[4][4];
#pragma unroll
  for (int a = 0; a < 4; ++a)
#pragma unroll
    for (int c = 0; c < 4; ++c) acc[a][c] = 0.f;

  for (int ic = 0; ic < 16; ++ic) {
    int i0 = ic * 64;
    __syncthreads();
#pragma unroll
    for (int r = 0; r < 16; ++r) {
      int idx = r * 256 + tid;
      int ii = idx >> 6, cc = idx & 63;
      xs[idx] = x[(b * CE + i0 + ii) * TT + t0 + cc];
      wls[idx] = winT[(i0 + ii) * 64 + cc];
    }
    __syncthreads();
#pragma unroll 16
    for (int ii = 0; ii < 64; ++ii) {
      float4 xv = *(const float4*)&xs[ii * 64 + tx * 4];
      float4 wv = *(const float4*)&wls[ii * 64 + ty * 4];
      float xa[4] = {xv.x, xv.y, xv.z, xv.w};
      float wa[4] = {wv.x, wv.y, wv.z, wv.w};
#pragma unroll
      for (int jo = 0; jo < 4; ++jo)
#pragma unroll
        for (int jt = 0; jt < 4; ++jt)
          acc[jo][jt] = fmaf(wa[jo], xa[jt], acc[jo][jt]);
    }
  }
#pragma unroll
  for (int jo = 0; jo < 4; ++jo) {
    int o = ty * 4 + jo;
    float4 v = make_float4(acc[jo][0], acc[jo][1], acc[jo][2], acc[jo][3]);
    *(float4*)&out[O_XPROJ + (size_t)(b * CC + o) * TT + t0 + tx * 4] = v;
  }
}

// ---------------------------------------------------------------------------
// Kernel 3: codes = argmin_k ( cbsq[k] - 2 * dot(e, cb_n[k]) ), e = l2norm(x_proj)
// grid = 256 (b*16 + t-tile of 128), block = 512 (tx=16 x ty=32), micro 8t x 4k.
// LDS = 32KB e-tile + 32KB cb-chunk = 64KB exactly.
// ---------------------------------------------------------------------------
__global__ __launch_bounds__(512) void dist_kernel(
    const float* __restrict__ ws, float* __restrict__ out,
    int* __restrict__ codes_i) {
  __shared__ float es[64 * 128];   // [c][t]  32 KB
  __shared__ float cbs[64 * 128];  // [c][kk] 32 KB
  int bid = blockIdx.x;
  int b = bid >> 4, t0 = (bid & 15) * 128;
  int tid = threadIdx.x;
  int tx = tid & 15, ty = tid >> 4;  // tx: 8 t's, ty: 4 k's
  const float* xproj = out + O_XPROJ;
  const float* cbT = ws + W_CBT;
  const float* cbsq = ws + W_CBSQ;

  // stage x_proj tile
#pragma unroll
  for (int r = 0; r < 16; ++r) {
    int idx = r * 512 + tid;
    int c = idx >> 7, t = idx & 127;
    es[idx] = xproj[(size_t)(b * CC + c) * TT + t0 + t];
  }
  __syncthreads();
  // l2-normalize each t-column (match reference: x / max(norm, eps), IEEE div)
  if (tid < 128) {
    int t = tid;
    float s = 0.f;
    for (int c = 0; c < 64; ++c) { float v = es[c * 128 + t]; s += v * v; }
    float dn = fmaxf(sqrtf(s), 1e-12f);
    for (int c = 0; c < 64; ++c) es[c * 128 + t] = es[c * 128 + t] / dn;
  }

  float best[8]; int bidx[8];
#pragma unroll
  for (int i = 0; i < 8; ++i) { best[i] = 3.4e38f; bidx[i] = 0; }

  for (int kc = 0; kc < 32; ++kc) {
    int k0 = kc * 128;
    __syncthreads();
#pragma unroll
    for (int r = 0; r < 16; ++r) {
      int idx = r * 512 + tid;
      int c = idx >> 7, kk = idx & 127;
      cbs[idx] = cbT[c * KK + k0 + kk];
    }
    __syncthreads();
    float acc[8][4];
#pragma unroll
    for (int i = 0; i < 8; ++i)
#pragma unroll
      for (int j = 0; j < 4; ++j) acc[i][j] = 0.f;
#pragma unroll 8
    for (int c = 0; c < 64; ++c) {
      float4 e0 = *(const float4*)&es[c * 128 + tx * 8];
      float4 e1 = *(const float4*)&es[c * 128 + tx * 8 + 4];
      float4 cv4 = *(const float4*)&cbs[c * 128 + ty * 4];
      float ev[8] = {e0.x, e0.y, e0.z, e0.w, e1.x, e1.y, e1.z, e1.w};
      float ca[4] = {cv4.x, cv4.y, cv4.z, cv4.w};
#pragma unroll
      for (int i = 0; i < 8; ++i)
#pragma unroll
        for (int j = 0; j < 4; ++j)
          acc[i][j] = fmaf(ev[i], ca[j], acc[i][j]);
    }
    float4 cq4 = *(const float4*)&cbsq[k0 + ty * 4];
    float cqa[4] = {cq4.x, cq4.y, cq4.z, cq4.w};
#pragma unroll
    for (int j = 0; j < 4; ++j) {
      int k = k0 + ty * 4 + j;
#pragma unroll
      for (int i = 0; i < 8; ++i) {
        float sc = cqa[j] - 2.f * acc[i][j];
        if (sc < best[i]) { best[i] = sc; bidx[i] = k; }  // strict <: first min kept
      }
    }
  }
  __syncthreads();
  // cross-ty argmin reduce (reuse LDS)
  float* rsc = es;           // 32*128 floats
  int* rix = (int*)cbs;      // 32*128 ints
#pragma unroll
  for (int i = 0; i < 8; ++i) {
    int t = tx * 8 + i;
    rsc[ty * 128 + t] = best[i];
    rix[ty * 128 + t] = bidx[i];
  }
  __syncthreads();
  if (tid < 128) {
    int t = tid;
    float bs = rsc[t]; int bi = rix[t];
    for (int yy = 1; yy < 32; ++yy) {
      float s = rsc[yy * 128 + t]; int ix = rix[yy * 128 + t];
      if (s < bs || (s == bs && ix < bi)) { bs = s; bi = ix; }
    }
    int gt = b * TT + t0 + t;
    out[O_CODES + gt] = (float)bi;
    codes_i[gt] = bi;
  }
}

// ---------------------------------------------------------------------------
// Kernel 4: q = codebook[codes]; quantized_proj = q; loss partials;
//           quantized[b,o,t] = sum_c W_out[o,c] * q[b,c,t]
// grid = 512 (b*32 + t-tile 64), block = 256.
// ---------------------------------------------------------------------------
__global__ __launch_bounds__(256) void gather_kernel(
    const float* __restrict__ cb, const float* __restrict__ ws,
    const int* __restrict__ codes_i, float* __restrict__ out,
    float* __restrict__ loss_acc) {
  __shared__ float qs[64 * 64];   // [c][t]
  __shared__ float wos[64 * 64];  // [c][oo]
  __shared__ float red[4];
  int bid = blockIdx.x;
  int b = bid >> 5, t0 = (bid & 31) * 64;
  int tid = threadIdx.x;
  int tx = tid & 15, ty = tid >> 4;

  // gather q tile: 4 threads per t, each loads 16 channels
  {
    int t = tid >> 2, c0 = (tid & 3) * 16;
    int k = codes_i[b * TT + t0 + t];
    const float4* cbr = (const float4*)(cb + (size_t)k * CC + c0);
    float4 r0 = cbr[0], r1 = cbr[1], r2 = cbr[2], r3 = cbr[3];
    float va[16] = {r0.x, r0.y, r0.z, r0.w, r1.x, r1.y, r1.z, r1.w,
                    r2.x, r2.y, r2.z, r2.w, r3.x, r3.y, r3.z, r3.w};
#pragma unroll
    for (int j = 0; j < 16; ++j) qs[(c0 + j) * 64 + t] = va[j];
  }
  __syncthreads();

  // quantized_proj write + loss partial
  float ls = 0.f;
#pragma unroll
  for (int r = 0; r < 16; ++r) {
    int idx = r * 256 + tid;
    int c = idx >> 6, t = idx & 63;
    float q = qs[idx];
    size_t g = (size_t)(b * CC + c) * TT + t0 + t;
    float xp = out[O_XPROJ + g];
    out[O_QPROJ + g] = q;
    float d = xp - q;
    ls = fmaf(d, d, ls);
  }
  for (int off = 32; off; off >>= 1) ls += __shfl_down(ls, off);
  if ((tid & 63) == 0) red[tid >> 6] = ls;
  __syncthreads();
  if (tid == 0) atomicAdd(loss_acc, red[0] + red[1] + red[2] + red[3]);

  // output GEMM: loop o-chunks of 64
  const float* woT = ws + W_WOUTT;
  for (int oc = 0; oc < 16; ++oc) {
    int o0 = oc * 64;
    __syncthreads();
#pragma unroll
    for (int r = 0; r < 16; ++r) {
      int idx = r * 256 + tid;
      int c = idx >> 6, oo = idx & 63;
      wos[idx] = woT[c * CE + o0 + oo];
    }
    __syncthreads();
    float acc[4][4];
#pragma unroll
    for (int a = 0; a < 4; ++a)
#pragma unroll
      for (int c2 = 0; c2 < 4; ++c2) acc[a][c2] = 0.f;
#pragma unroll 16
    for (int c = 0; c < 64; ++c) {
      float4 qv = *(const float4*)&qs[c * 64 + tx * 4];
      float4 wv = *(const float4*)&wos[c * 64 + ty * 4];
      float qa[4] = {qv.x, qv.y, qv.z, qv.w};
      float wa[4] = {wv.x, wv.y, wv.z, wv.w};
#pragma unroll
      for (int jo = 0; jo < 4; ++jo)
#pragma unroll
        for (int jt = 0; jt < 4; ++jt)
          acc[jo][jt] = fmaf(wa[jo], qa[jt], acc[jo][jt]);
    }
#pragma unroll
    for (int jo = 0; jo < 4; ++jo) {
      int o = o0 + ty * 4 + jo;
      float4 v = make_float4(acc[jo][0], acc[jo][1], acc[jo][2], acc[jo][3]);
      *(float4*)&out[O_QUANT + (size_t)(b * CE + o) * TT + t0 + tx * 4] = v;
    }
  }
}

// ---------------------------------------------------------------------------
// Kernel 5: finalize losses (codebook_loss == commit_loss in fwd value)
// ---------------------------------------------------------------------------
__global__ void finalize_kernel(const float* __restrict__ ws, float* __restrict__ out) {
  if (threadIdx.x == 0 && blockIdx.x == 0) {
    float l = ws[W_LOSS] / 2097152.f;  // B*CC*T
    out[O_CBL] = l;
    out[O_CML] = l;
  }
}

extern "C" void kernel_launch(void* const* d_in, const int* in_sizes, int n_in,
                              void* d_out, int out_size, void* d_ws, size_t ws_size,
                              hipStream_t stream) {
  const float* x     = (const float*)d_in[0];
  const float* v_in  = (const float*)d_in[1];
  const float* g_in  = (const float*)d_in[2];
  const float* v_out = (const float*)d_in[3];
  const float* g_out = (const float*)d_in[4];
  const float* cb    = (const float*)d_in[5];
  float* out = (float*)d_out;
  float* ws  = (float*)d_ws;
  int* codes_i = (int*)(ws + W_CODES);

  prep_kernel<<<64 + 1024 + 4096, 64, 0, stream>>>(v_in, g_in, v_out, g_out, cb, ws);
  proj_in_kernel<<<512, 256, 0, stream>>>(x, ws, out);
  dist_kernel<<<256, 512, 0, stream>>>(ws, out, codes_i);
  gather_kernel<<<512, 256, 0, stream>>>(cb, ws, codes_i, out, ws + W_LOSS);
  finalize_kernel<<<1, 64, 0, stream>>>(ws, out);
}

// Round 2
// 446.808 us; speedup vs baseline: 1.3272x; 1.3272x over previous
//
#include <hip/hip_runtime.h>
#include <math.h>

// Problem constants
#define BB 16
#define CE 1024
#define TT 2048
#define KK 4096
#define CC 64

// d_out offsets (floats): codes (B,T) | quantized (B,CE,T) | cb_loss | commit_loss
//                         | x_proj (B,CC,T) | quantized_proj (B,CC,T)
#define O_CODES 0
#define O_QUANT 32768
#define O_CBL   33587200
#define O_CML   33587201
#define O_XPROJ 33587202
#define O_QPROJ 35684354

// workspace offsets (floats)
#define W_WINT  0         // W_in transposed  [i=1024][o=64]
#define W_WOUTT 65536     // W_out transposed [c=64][o=1024]
#define W_CBSQ  131072    // sum(cb_n^2) per k [4096]
#define W_NORMS 135168    // per-(b,t) l2 norm of x_proj [32768]
#define W_CODES 167936    // int codes [32768]
#define W_PB    200704    // partial best score [4][32768]
#define W_PIDX  331776    // partial best idx   [4][32768] (int)
#define W_LOSS  462848    // float accumulator
#define W_BF    524288    // cb frags fp16 hi|lo, 262144 floats (1 MB)

typedef __attribute__((ext_vector_type(8))) _Float16 half8;
typedef __attribute__((ext_vector_type(4))) float f32x4;

// ---------------------------------------------------------------------------
// Kernel 1: weight-norm W_in/W_out; codebook -> cbsq + fp16 hi/lo B-frags.
// B-frag layout (mfma_f32_16x16x32_f16): lane = ((c>>3)&3)*16 + (k&15),
// j = c&7, ki = c>>5, ntile = k>>4. half index = (((term*256+nt)*2+ki)*64+lane)*8+j
// ---------------------------------------------------------------------------
__global__ __launch_bounds__(64) void prep_kernel(
    const float* __restrict__ v_in, const float* __restrict__ g_in,
    const float* __restrict__ v_out, const float* __restrict__ g_out,
    const float* __restrict__ cb, float* __restrict__ ws) {
  int bid = blockIdx.x, tid = threadIdx.x;
  if (bid == 0 && tid == 0) ws[W_LOSS] = 0.f;
  if (bid < 64) {
    int o = bid;
    float s = 0.f;
    for (int i = tid; i < CE; i += 64) { float v = v_in[o * CE + i]; s += v * v; }
    for (int off = 32; off; off >>= 1) s += __shfl_down(s, off);
    s = __shfl(s, 0);
    float norm = sqrtf(s);
    float g = g_in[o];
    for (int i = tid; i < CE; i += 64)
      ws[W_WINT + i * 64 + o] = (g * v_in[o * CE + i]) / norm;
  } else if (bid < 64 + CE) {
    int o = bid - 64;
    float v = v_out[o * CC + tid];
    float s = v * v;
    for (int off = 32; off; off >>= 1) s += __shfl_down(s, off);
    s = __shfl(s, 0);
    ws[W_WOUTT + tid * CE + o] = (g_out[o] * v) / sqrtf(s);
  } else {
    int k = bid - 64 - CE;
    int c = tid;
    float v = cb[k * CC + c];
    float s = v * v;
    for (int off = 32; off; off >>= 1) s += __shfl_down(s, off);
    s = __shfl(s, 0);
    float n = fmaxf(sqrtf(s), 1e-12f);
    float cn = v / n;
    float s2 = cn * cn;
    for (int off = 32; off; off >>= 1) s2 += __shfl_down(s2, off);
    if (tid == 0) ws[W_CBSQ + k] = s2;
    // fp16 split frags
    _Float16 hi = (_Float16)cn;
    _Float16 lo = (_Float16)(cn - (float)hi);
    _Float16* bfh = (_Float16*)(ws + W_BF);
    int ntile = k >> 4, ki = c >> 5;
    int lane = ((c >> 3) & 3) * 16 + (k & 15);
    int j = c & 7;
    int idx = (((ntile * 2 + ki) * 64 + lane) << 3) + j;
    bfh[idx] = hi;
    bfh[262144 + idx] = lo;
  }
}

// ---------------------------------------------------------------------------
// Kernel 2: x_proj[b,o,t] = sum_i W_in[o,i] * x[b,i,t]  (unchanged this round)
// ---------------------------------------------------------------------------
__global__ __launch_bounds__(256) void proj_in_kernel(
    const float* __restrict__ x, const float* __restrict__ ws,
    float* __restrict__ out) {
  __shared__ float xs[64 * 64];
  __shared__ float wls[64 * 64];
  int bid = blockIdx.x;
  int b = bid >> 5, t0 = (bid & 31) * 64;
  int tid = threadIdx.x;
  int tx = tid & 15, ty = tid >> 4;
  const float* winT = ws + W_WINT;
  float acc[4][4];
#pragma unroll
  for (int a = 0; a < 4; ++a)
#pragma unroll
    for (int c = 0; c < 4; ++c) acc[a][c] = 0.f;

  for (int ic = 0; ic < 16; ++ic) {
    int i0 = ic * 64;
    __syncthreads();
#pragma unroll
    for (int r = 0; r < 16; ++r) {
      int idx = r * 256 + tid;
      int ii = idx >> 6, cc = idx & 63;
      xs[idx] = x[(b * CE + i0 + ii) * TT + t0 + cc];
      wls[idx] = winT[(i0 + ii) * 64 + cc];
    }
    __syncthreads();
#pragma unroll 16
    for (int ii = 0; ii < 64; ++ii) {
      float4 xv = *(const float4*)&xs[ii * 64 + tx * 4];
      float4 wv = *(const float4*)&wls[ii * 64 + ty * 4];
      float xa[4] = {xv.x, xv.y, xv.z, xv.w};
      float wa[4] = {wv.x, wv.y, wv.z, wv.w};
#pragma unroll
      for (int jo = 0; jo < 4; ++jo)
#pragma unroll
        for (int jt = 0; jt < 4; ++jt)
          acc[jo][jt] = fmaf(wa[jo], xa[jt], acc[jo][jt]);
    }
  }
#pragma unroll
  for (int jo = 0; jo < 4; ++jo) {
    int o = ty * 4 + jo;
    float4 v = make_float4(acc[jo][0], acc[jo][1], acc[jo][2], acc[jo][3]);
    *(float4*)&out[O_XPROJ + (size_t)(b * CC + o) * TT + t0 + tx * 4] = v;
  }
}

// ---------------------------------------------------------------------------
// Kernel 3: per-(b,t) l2 norm of x_proj. grid 128 x 256.
// ---------------------------------------------------------------------------
__global__ __launch_bounds__(256) void norm_kernel(
    const float* __restrict__ xproj, float* __restrict__ norms) {
  int blk = blockIdx.x;
  int b = blk >> 3, t = (blk & 7) * 256 + threadIdx.x;
  const float* p = xproj + (size_t)b * CC * TT + t;
  float s = 0.f;
#pragma unroll 8
  for (int c = 0; c < 64; ++c) { float v = p[c * TT]; s = fmaf(v, v, s); }
  norms[b * TT + t] = fmaxf(sqrtf(s), 1e-12f);
}

// ---------------------------------------------------------------------------
// Kernel 4: MFMA distance argmin. grid 512 = 128 t-blocks x 4 k-splits.
// block 256 = 4 waves, each wave: 4 bands of 16 t (t-tile 256 per block).
// A (e = x_proj/norm, fp16 hi/lo) in registers; B (cb frags) via LDS chunks.
// score = cbsq[k] - 2*dot -> per-lane argmin -> butterfly -> partials.
// ---------------------------------------------------------------------------
__global__ __launch_bounds__(256) void dist_kernel(
    const float* __restrict__ xproj, const float* __restrict__ norms,
    const float* __restrict__ cbsq, const uint4* __restrict__ bf,
    float* __restrict__ pbest, int* __restrict__ pidx) {
  __shared__ uint4 ldsB[2048];  // 32 KB: [0:1024) hi chunk, [1024:2048) lo chunk
  int tid = threadIdx.x;
  int l = tid & 63, w = tid >> 6;
  int blk = blockIdx.x;
  int tb = blk >> 2, ks = blk & 3;
  int b = tb >> 3, t0 = (tb & 7) * 256;
  int m = l & 15, q = l >> 4;

  // Phase 1: build A-frags in registers
  half8 Ahi[4][2], Alo[4][2];
  const float* xpB = xproj + (size_t)b * CC * TT;
#pragma unroll
  for (int bd = 0; bd < 4; ++bd) {
    int t = t0 + w * 64 + bd * 16 + m;
    float n = norms[b * TT + t];
#pragma unroll
    for (int ki = 0; ki < 2; ++ki) {
      int cbase = ki * 32 + q * 8;
#pragma unroll
      for (int j = 0; j < 8; ++j) {
        float v = xpB[(cbase + j) * TT + t] / n;
        _Float16 h = (_Float16)v;
        Ahi[bd][ki][j] = h;
        Alo[bd][ki][j] = (_Float16)(v - (float)h);
      }
    }
  }

  float best[4][4];
  int bidx[4][4];
#pragma unroll
  for (int bd = 0; bd < 4; ++bd)
#pragma unroll
    for (int r = 0; r < 4; ++r) { best[bd][r] = 3.4e38f; bidx[bd][r] = 0; }

  for (int cc = 0; cc < 8; ++cc) {
    int nt0 = ks * 64 + cc * 8;  // global ntile of chunk start (8 ntiles)
    __syncthreads();
#pragma unroll
    for (int r = 0; r < 4; ++r) {
      int u = r * 256 + tid;  // 0..1023 uint4 units (16 KB per term)
      ldsB[u] = bf[nt0 * 128 + u];
      ldsB[1024 + u] = bf[32768 + nt0 * 128 + u];
    }
    __syncthreads();
#pragma unroll
    for (int ntl = 0; ntl < 8; ++ntl) {
      int kbase = (nt0 + ntl) * 16;
      float cq = cbsq[kbase + m];
      half8 Bhi0 = *(const half8*)&ldsB[ntl * 128 + l];
      half8 Bhi1 = *(const half8*)&ldsB[ntl * 128 + 64 + l];
      half8 Blo0 = *(const half8*)&ldsB[1024 + ntl * 128 + l];
      half8 Blo1 = *(const half8*)&ldsB[1024 + ntl * 128 + 64 + l];
      f32x4 acc[4];
#pragma unroll
      for (int bd = 0; bd < 4; ++bd) acc[bd] = (f32x4){0.f, 0.f, 0.f, 0.f};
#pragma unroll
      for (int bd = 0; bd < 4; ++bd)
        acc[bd] = __builtin_amdgcn_mfma_f32_16x16x32_f16(Ahi[bd][0], Bhi0, acc[bd], 0, 0, 0);
#pragma unroll
      for (int bd = 0; bd < 4; ++bd)
        acc[bd] = __builtin_amdgcn_mfma_f32_16x16x32_f16(Ahi[bd][1], Bhi1, acc[bd], 0, 0, 0);
#pragma unroll
      for (int bd = 0; bd < 4; ++bd)
        acc[bd] = __builtin_amdgcn_mfma_f32_16x16x32_f16(Alo[bd][0], Bhi0, acc[bd], 0, 0, 0);
#pragma unroll
      for (int bd = 0; bd < 4; ++bd)
        acc[bd] = __builtin_amdgcn_mfma_f32_16x16x32_f16(Alo[bd][1], Bhi1, acc[bd], 0, 0, 0);
#pragma unroll
      for (int bd = 0; bd < 4; ++bd)
        acc[bd] = __builtin_amdgcn_mfma_f32_16x16x32_f16(Ahi[bd][0], Blo0, acc[bd], 0, 0, 0);
#pragma unroll
      for (int bd = 0; bd < 4; ++bd)
        acc[bd] = __builtin_amdgcn_mfma_f32_16x16x32_f16(Ahi[bd][1], Blo1, acc[bd], 0, 0, 0);
      int kl = kbase + m;
#pragma unroll
      for (int bd = 0; bd < 4; ++bd)
#pragma unroll
        for (int r = 0; r < 4; ++r) {
          float sc = fmaf(-2.f, acc[bd][r], cq);
          if (sc < best[bd][r]) { best[bd][r] = sc; bidx[bd][r] = kl; }
        }
    }
  }

  // butterfly argmin across lane bits 0..3 (the 16 k-residues)
#pragma unroll
  for (int st = 1; st < 16; st <<= 1) {
#pragma unroll
    for (int bd = 0; bd < 4; ++bd)
#pragma unroll
      for (int r = 0; r < 4; ++r) {
        float os = __shfl_xor(best[bd][r], st);
        int oi = __shfl_xor(bidx[bd][r], st);
        if (os < best[bd][r] || (os == best[bd][r] && oi < bidx[bd][r])) {
          best[bd][r] = os;
          bidx[bd][r] = oi;
        }
      }
  }
  if (m == 0) {
#pragma unroll
    for (int bd = 0; bd < 4; ++bd)
#pragma unroll
      for (int r = 0; r < 4; ++r) {
        int t = t0 + w * 64 + bd * 16 + q * 4 + r;
        int gt = b * TT + t;
        pbest[ks * 32768 + gt] = best[bd][r];
        pidx[ks * 32768 + gt] = bidx[bd][r];
      }
  }
}

// ---------------------------------------------------------------------------
// Kernel 5: merge the 4 k-split partials -> codes. grid 128 x 256.
// ---------------------------------------------------------------------------
__global__ __launch_bounds__(256) void merge_kernel(
    const float* __restrict__ pbest, const int* __restrict__ pidx,
    float* __restrict__ out, int* __restrict__ codes_i) {
  int gt = blockIdx.x * 256 + threadIdx.x;
  float bs = pbest[gt];
  int bi = pidx[gt];
#pragma unroll
  for (int s = 1; s < 4; ++s) {
    float s2 = pbest[s * 32768 + gt];
    int i2 = pidx[s * 32768 + gt];
    if (s2 < bs || (s2 == bs && i2 < bi)) { bs = s2; bi = i2; }
  }
  out[O_CODES + gt] = (float)bi;
  codes_i[gt] = bi;
}

// ---------------------------------------------------------------------------
// Kernel 6: q = codebook[codes]; quantized_proj = q; loss; W_out GEMM.
// ---------------------------------------------------------------------------
__global__ __launch_bounds__(256) void gather_kernel(
    const float* __restrict__ cb, const float* __restrict__ ws,
    const int* __restrict__ codes_i, float* __restrict__ out,
    float* __restrict__ loss_acc) {
  __shared__ float qs[64 * 64];
  __shared__ float wos[64 * 64];
  __shared__ float red[4];
  int bid = blockIdx.x;
  int b = bid >> 5, t0 = (bid & 31) * 64;
  int tid = threadIdx.x;
  int tx = tid & 15, ty = tid >> 4;

  {
    int t = tid >> 2, c0 = (tid & 3) * 16;
    int k = codes_i[b * TT + t0 + t];
    const float4* cbr = (const float4*)(cb + (size_t)k * CC + c0);
    float4 r0 = cbr[0], r1 = cbr[1], r2 = cbr[2], r3 = cbr[3];
    float va[16] = {r0.x, r0.y, r0.z, r0.w, r1.x, r1.y, r1.z, r1.w,
                    r2.x, r2.y, r2.z, r2.w, r3.x, r3.y, r3.z, r3.w};
#pragma unroll
    for (int j = 0; j < 16; ++j) qs[(c0 + j) * 64 + t] = va[j];
  }
  __syncthreads();

  float ls = 0.f;
#pragma unroll
  for (int r = 0; r < 16; ++r) {
    int idx = r * 256 + tid;
    int c = idx >> 6, t = idx & 63;
    float q = qs[idx];
    size_t g = (size_t)(b * CC + c) * TT + t0 + t;
    float xp = out[O_XPROJ + g];
    out[O_QPROJ + g] = q;
    float d = xp - q;
    ls = fmaf(d, d, ls);
  }
  for (int off = 32; off; off >>= 1) ls += __shfl_down(ls, off);
  if ((tid & 63) == 0) red[tid >> 6] = ls;
  __syncthreads();
  if (tid == 0) atomicAdd(loss_acc, red[0] + red[1] + red[2] + red[3]);

  const float* woT = ws + W_WOUTT;
  for (int oc = 0; oc < 16; ++oc) {
    int o0 = oc * 64;
    __syncthreads();
#pragma unroll
    for (int r = 0; r < 16; ++r) {
      int idx = r * 256 + tid;
      int c = idx >> 6, oo = idx & 63;
      wos[idx] = woT[c * CE + o0 + oo];
    }
    __syncthreads();
    float acc[4][4];
#pragma unroll
    for (int a = 0; a < 4; ++a)
#pragma unroll
      for (int c2 = 0; c2 < 4; ++c2) acc[a][c2] = 0.f;
#pragma unroll 16
    for (int c = 0; c < 64; ++c) {
      float4 qv = *(const float4*)&qs[c * 64 + tx * 4];
      float4 wv = *(const float4*)&wos[c * 64 + ty * 4];
      float qa[4] = {qv.x, qv.y, qv.z, qv.w};
      float wa[4] = {wv.x, wv.y, wv.z, wv.w};
#pragma unroll
      for (int jo = 0; jo < 4; ++jo)
#pragma unroll
        for (int jt = 0; jt < 4; ++jt)
          acc[jo][jt] = fmaf(wa[jo], qa[jt], acc[jo][jt]);
    }
#pragma unroll
    for (int jo = 0; jo < 4; ++jo) {
      int o = o0 + ty * 4 + jo;
      float4 v = make_float4(acc[jo][0], acc[jo][1], acc[jo][2], acc[jo][3]);
      *(float4*)&out[O_QUANT + (size_t)(b * CE + o) * TT + t0 + tx * 4] = v;
    }
  }
}

// ---------------------------------------------------------------------------
// Kernel 7: finalize losses
// ---------------------------------------------------------------------------
__global__ void finalize_kernel(const float* __restrict__ ws, float* __restrict__ out) {
  if (threadIdx.x == 0 && blockIdx.x == 0) {
    float l = ws[W_LOSS] / 2097152.f;  // B*CC*T
    out[O_CBL] = l;
    out[O_CML] = l;
  }
}

extern "C" void kernel_launch(void* const* d_in, const int* in_sizes, int n_in,
                              void* d_out, int out_size, void* d_ws, size_t ws_size,
                              hipStream_t stream) {
  const float* x     = (const float*)d_in[0];
  const float* v_in  = (const float*)d_in[1];
  const float* g_in  = (const float*)d_in[2];
  const float* v_out = (const float*)d_in[3];
  const float* g_out = (const float*)d_in[4];
  const float* cb    = (const float*)d_in[5];
  float* out = (float*)d_out;
  float* ws  = (float*)d_ws;
  int* codes_i = (int*)(ws + W_CODES);

  prep_kernel<<<64 + 1024 + 4096, 64, 0, stream>>>(v_in, g_in, v_out, g_out, cb, ws);
  proj_in_kernel<<<512, 256, 0, stream>>>(x, ws, out);
  norm_kernel<<<128, 256, 0, stream>>>(out + O_XPROJ, ws + W_NORMS);
  dist_kernel<<<512, 256, 0, stream>>>(out + O_XPROJ, ws + W_NORMS,
                                       ws + W_CBSQ, (const uint4*)(ws + W_BF),
                                       ws + W_PB, (int*)(ws + W_PIDX));
  merge_kernel<<<128, 256, 0, stream>>>(ws + W_PB, (const int*)(ws + W_PIDX),
                                        out, codes_i);
  gather_kernel<<<512, 256, 0, stream>>>(cb, ws, codes_i, out, ws + W_LOSS);
  finalize_kernel<<<1, 64, 0, stream>>>(ws, out);
}

// Round 3
// 402.569 us; speedup vs baseline: 1.4730x; 1.1099x over previous
//
#include <hip/hip_runtime.h>
#include <math.h>

// Problem constants
#define BB 16
#define CE 1024
#define TT 2048
#define KK 4096
#define CC 64

// d_out offsets (floats): codes (B,T) | quantized (B,CE,T) | cb_loss | commit_loss
//                         | x_proj (B,CC,T) | quantized_proj (B,CC,T)
#define O_CODES 0
#define O_QUANT 32768
#define O_CBL   33587200
#define O_CML   33587201
#define O_XPROJ 33587202
#define O_QPROJ 35684354

// workspace offsets (floats)
#define W_WINF  0         // W_in fp16 frags hi|lo: half8[2][4][32][64] (1 MB)
#define W_WOUTF 262144    // W_out fp16 frags hi|lo: half8[2][64][2][64] (256 KB)
#define W_CBSQ  327680    // sum(cb_n^2) per k [4096]
#define W_NORMS 331776    // per-(b,t) l2 norm of x_proj [32768]
#define W_CODES 364544    // int codes [32768]
#define W_PB    397312    // partial best score [4][32768]
#define W_PIDX  528384    // partial best idx   [4][32768] (int)
#define W_LOSS  659456    // float accumulator (+pad)
#define W_BF    659520    // cb frags fp16 hi|lo, 262144 floats (1 MB)

typedef __attribute__((ext_vector_type(8))) _Float16 half8;
typedef __attribute__((ext_vector_type(4))) float f32x4;

// ---------------------------------------------------------------------------
// Kernel 1: weight-norm W_in/W_out -> fp16 hi/lo MFMA A-frags;
// codebook -> cbsq + fp16 hi/lo B-frags.
// Frag convention (16x16x32 f16), verified by round-2 dist pass:
//   A[m][k]: lane = ((k>>3)&3)*16 + (m&15), j = k&7
//   B[k][n]: lane = ((k>>3)&3)*16 + (n&15), j = k&7
//   D: row(m) = (lane>>4)*4 + reg, col(n) = lane&15
// ---------------------------------------------------------------------------
__global__ __launch_bounds__(64) void prep_kernel(
    const float* __restrict__ v_in, const float* __restrict__ g_in,
    const float* __restrict__ v_out, const float* __restrict__ g_out,
    const float* __restrict__ cb, float* __restrict__ ws) {
  int bid = blockIdx.x, tid = threadIdx.x;
  if (bid == 0 && tid == 0) ws[W_LOSS] = 0.f;
  if (bid < 64) {
    // W_in row o (K=1024): frags half idx = (((term*4+ot)*32+ks)*64+lane)*8+j
    int o = bid;
    float s = 0.f;
    for (int i = tid; i < CE; i += 64) { float v = v_in[o * CE + i]; s += v * v; }
    for (int off = 32; off; off >>= 1) s += __shfl_down(s, off);
    s = __shfl(s, 0);
    float norm = sqrtf(s);
    float g = g_in[o];
    _Float16* wf = (_Float16*)(ws + W_WINF);
    int ot = o >> 4, m = o & 15;
    for (int i = tid; i < CE; i += 64) {
      float w = (g * v_in[o * CE + i]) / norm;
      _Float16 hi = (_Float16)w;
      _Float16 lo = (_Float16)(w - (float)hi);
      int ks = i >> 5, q = (i >> 3) & 3, j = i & 7;
      int lane = q * 16 + m;
      int base = ((ot * 32 + ks) * 64 + lane) * 8 + j;
      wf[base] = hi;                    // term 0
      wf[65536 + base] = lo;            // term 1 (4*32*64*8 = 65536 halves)
    }
  } else if (bid < 64 + CE) {
    // W_out row o (K=64): frags half idx = (((term*64+ot)*2+ks)*64+lane)*8+j
    int o = bid - 64;
    int c = tid;
    float v = v_out[o * CC + c];
    float s = v * v;
    for (int off = 32; off; off >>= 1) s += __shfl_down(s, off);
    s = __shfl(s, 0);
    float w = (g_out[o] * v) / sqrtf(s);
    _Float16 hi = (_Float16)w;
    _Float16 lo = (_Float16)(w - (float)hi);
    _Float16* wf = (_Float16*)(ws + W_WOUTF);
    int ot = o >> 4, m = o & 15;
    int ks = c >> 5, q = (c >> 3) & 3, j = c & 7;
    int lane = q * 16 + m;
    int base = ((ot * 2 + ks) * 64 + lane) * 8 + j;
    wf[base] = hi;                      // term 0
    wf[131072 / 2 + base] = lo;         // term 1 (64*2*64*8 = 65536 halves)
  } else {
    // codebook row k: cbsq + B-frags (dist): idx = (((nt*2+ki)*64+lane)*8+j)
    int k = bid - 64 - CE;
    int c = tid;
    float v = cb[k * CC + c];
    float s = v * v;
    for (int off = 32; off; off >>= 1) s += __shfl_down(s, off);
    s = __shfl(s, 0);
    float n = fmaxf(sqrtf(s), 1e-12f);
    float cn = v / n;
    float s2 = cn * cn;
    for (int off = 32; off; off >>= 1) s2 += __shfl_down(s2, off);
    if (tid == 0) ws[W_CBSQ + k] = s2;
    _Float16 hi = (_Float16)cn;
    _Float16 lo = (_Float16)(cn - (float)hi);
    _Float16* bfh = (_Float16*)(ws + W_BF);
    int ntile = k >> 4, ki = c >> 5;
    int lane = ((c >> 3) & 3) * 16 + (k & 15);
    int j = c & 7;
    int idx = (((ntile * 2 + ki) * 64 + lane) << 3) + j;
    bfh[idx] = hi;
    bfh[262144 + idx] = lo;
  }
}

// ---------------------------------------------------------------------------
// Kernel 2: x_proj = W_in * x via fp16-split MFMA; fused per-t l2 norm.
// grid 512 = b*32 + t-chunk(64); block 256 = 4 waves x 16 t each; all 64 o.
// ---------------------------------------------------------------------------
__global__ __launch_bounds__(256) void proj_in_kernel(
    const float* __restrict__ x, const half8* __restrict__ wf,
    float* __restrict__ out, float* __restrict__ norms) {
  int tid = threadIdx.x;
  int w = tid >> 6, l = tid & 63;
  int n = l & 15, q = l >> 4;
  int blk = blockIdx.x;
  int b = blk >> 5, t0 = (blk & 31) * 64;
  int t = t0 + w * 16 + n;
  const float* xp = x + (size_t)b * CE * TT + t;

  f32x4 acc[4];
#pragma unroll
  for (int ot = 0; ot < 4; ++ot) acc[ot] = (f32x4){0.f, 0.f, 0.f, 0.f};

  for (int ks = 0; ks < 32; ++ks) {
    int kb = ks * 32 + q * 8;
    float v[8];
#pragma unroll
    for (int j = 0; j < 8; ++j) v[j] = xp[(size_t)(kb + j) * TT];
    half8 xh, xl;
#pragma unroll
    for (int j = 0; j < 8; ++j) xh[j] = (_Float16)v[j];
#pragma unroll
    for (int j = 0; j < 8; ++j) xl[j] = (_Float16)(v[j] - (float)xh[j]);
    half8 wh[4], wl[4];
#pragma unroll
    for (int ot = 0; ot < 4; ++ot) {
      wh[ot] = wf[(ot * 32 + ks) * 64 + l];
      wl[ot] = wf[8192 + (ot * 32 + ks) * 64 + l];
    }
#pragma unroll
    for (int ot = 0; ot < 4; ++ot)
      acc[ot] = __builtin_amdgcn_mfma_f32_16x16x32_f16(wh[ot], xh, acc[ot], 0, 0, 0);
#pragma unroll
    for (int ot = 0; ot < 4; ++ot)
      acc[ot] = __builtin_amdgcn_mfma_f32_16x16x32_f16(wh[ot], xl, acc[ot], 0, 0, 0);
#pragma unroll
    for (int ot = 0; ot < 4; ++ot)
      acc[ot] = __builtin_amdgcn_mfma_f32_16x16x32_f16(wl[ot], xh, acc[ot], 0, 0, 0);
  }

  float s = 0.f;
#pragma unroll
  for (int ot = 0; ot < 4; ++ot) {
#pragma unroll
    for (int r = 0; r < 4; ++r) {
      float vv = acc[ot][r];
      out[O_XPROJ + (size_t)(b * CC + ot * 16 + q * 4 + r) * TT + t] = vv;
      s = fmaf(vv, vv, s);
    }
  }
  s += __shfl_xor(s, 16);
  s += __shfl_xor(s, 32);
  if (q == 0) norms[b * TT + t] = fmaxf(sqrtf(s), 1e-12f);
}

// ---------------------------------------------------------------------------
// Kernel 3: MFMA distance argmin (unchanged from round 2).
// grid 512 = 128 t-blocks x 4 k-splits; block 256 = 4 waves x 64 t.
// ---------------------------------------------------------------------------
__global__ __launch_bounds__(256) void dist_kernel(
    const float* __restrict__ xproj, const float* __restrict__ norms,
    const float* __restrict__ cbsq, const uint4* __restrict__ bf,
    float* __restrict__ pbest, int* __restrict__ pidx) {
  __shared__ uint4 ldsB[2048];
  int tid = threadIdx.x;
  int l = tid & 63, w = tid >> 6;
  int blk = blockIdx.x;
  int tb = blk >> 2, ks = blk & 3;
  int b = tb >> 3, t0 = (tb & 7) * 256;
  int m = l & 15, q = l >> 4;

  half8 Ahi[4][2], Alo[4][2];
  const float* xpB = xproj + (size_t)b * CC * TT;
#pragma unroll
  for (int bd = 0; bd < 4; ++bd) {
    int t = t0 + w * 64 + bd * 16 + m;
    float n = norms[b * TT + t];
#pragma unroll
    for (int ki = 0; ki < 2; ++ki) {
      int cbase = ki * 32 + q * 8;
#pragma unroll
      for (int j = 0; j < 8; ++j) {
        float v = xpB[(cbase + j) * TT + t] / n;
        _Float16 h = (_Float16)v;
        Ahi[bd][ki][j] = h;
        Alo[bd][ki][j] = (_Float16)(v - (float)h);
      }
    }
  }

  float best[4][4];
  int bidx[4][4];
#pragma unroll
  for (int bd = 0; bd < 4; ++bd)
#pragma unroll
    for (int r = 0; r < 4; ++r) { best[bd][r] = 3.4e38f; bidx[bd][r] = 0; }

  for (int cc = 0; cc < 8; ++cc) {
    int nt0 = ks * 64 + cc * 8;
    __syncthreads();
#pragma unroll
    for (int r = 0; r < 4; ++r) {
      int u = r * 256 + tid;
      ldsB[u] = bf[nt0 * 128 + u];
      ldsB[1024 + u] = bf[32768 + nt0 * 128 + u];
    }
    __syncthreads();
#pragma unroll
    for (int ntl = 0; ntl < 8; ++ntl) {
      int kbase = (nt0 + ntl) * 16;
      float cq = cbsq[kbase + m];
      half8 Bhi0 = *(const half8*)&ldsB[ntl * 128 + l];
      half8 Bhi1 = *(const half8*)&ldsB[ntl * 128 + 64 + l];
      half8 Blo0 = *(const half8*)&ldsB[1024 + ntl * 128 + l];
      half8 Blo1 = *(const half8*)&ldsB[1024 + ntl * 128 + 64 + l];
      f32x4 acc[4];
#pragma unroll
      for (int bd = 0; bd < 4; ++bd) acc[bd] = (f32x4){0.f, 0.f, 0.f, 0.f};
#pragma unroll
      for (int bd = 0; bd < 4; ++bd)
        acc[bd] = __builtin_amdgcn_mfma_f32_16x16x32_f16(Ahi[bd][0], Bhi0, acc[bd], 0, 0, 0);
#pragma unroll
      for (int bd = 0; bd < 4; ++bd)
        acc[bd] = __builtin_amdgcn_mfma_f32_16x16x32_f16(Ahi[bd][1], Bhi1, acc[bd], 0, 0, 0);
#pragma unroll
      for (int bd = 0; bd < 4; ++bd)
        acc[bd] = __builtin_amdgcn_mfma_f32_16x16x32_f16(Alo[bd][0], Bhi0, acc[bd], 0, 0, 0);
#pragma unroll
      for (int bd = 0; bd < 4; ++bd)
        acc[bd] = __builtin_amdgcn_mfma_f32_16x16x32_f16(Alo[bd][1], Bhi1, acc[bd], 0, 0, 0);
#pragma unroll
      for (int bd = 0; bd < 4; ++bd)
        acc[bd] = __builtin_amdgcn_mfma_f32_16x16x32_f16(Ahi[bd][0], Blo0, acc[bd], 0, 0, 0);
#pragma unroll
      for (int bd = 0; bd < 4; ++bd)
        acc[bd] = __builtin_amdgcn_mfma_f32_16x16x32_f16(Ahi[bd][1], Blo1, acc[bd], 0, 0, 0);
      int kl = kbase + m;
#pragma unroll
      for (int bd = 0; bd < 4; ++bd)
#pragma unroll
        for (int r = 0; r < 4; ++r) {
          float sc = fmaf(-2.f, acc[bd][r], cq);
          if (sc < best[bd][r]) { best[bd][r] = sc; bidx[bd][r] = kl; }
        }
    }
  }

#pragma unroll
  for (int st = 1; st < 16; st <<= 1) {
#pragma unroll
    for (int bd = 0; bd < 4; ++bd)
#pragma unroll
      for (int r = 0; r < 4; ++r) {
        float os = __shfl_xor(best[bd][r], st);
        int oi = __shfl_xor(bidx[bd][r], st);
        if (os < best[bd][r] || (os == best[bd][r] && oi < bidx[bd][r])) {
          best[bd][r] = os;
          bidx[bd][r] = oi;
        }
      }
  }
  if (m == 0) {
#pragma unroll
    for (int bd = 0; bd < 4; ++bd)
#pragma unroll
      for (int r = 0; r < 4; ++r) {
        int t = t0 + w * 64 + bd * 16 + q * 4 + r;
        int gt = b * TT + t;
        pbest[ks * 32768 + gt] = best[bd][r];
        pidx[ks * 32768 + gt] = bidx[bd][r];
      }
  }
}

// ---------------------------------------------------------------------------
// Kernel 4: merge k-split partials -> codes.
// ---------------------------------------------------------------------------
__global__ __launch_bounds__(256) void merge_kernel(
    const float* __restrict__ pbest, const int* __restrict__ pidx,
    float* __restrict__ out, int* __restrict__ codes_i) {
  int gt = blockIdx.x * 256 + threadIdx.x;
  float bs = pbest[gt];
  int bi = pidx[gt];
#pragma unroll
  for (int s = 1; s < 4; ++s) {
    float s2 = pbest[s * 32768 + gt];
    int i2 = pidx[s * 32768 + gt];
    if (s2 < bs || (s2 == bs && i2 < bi)) { bs = s2; bi = i2; }
  }
  out[O_CODES + gt] = (float)bi;
  codes_i[gt] = bi;
}

// ---------------------------------------------------------------------------
// Kernel 5: gather + quantized_proj + loss + W_out GEMM via fp16-split MFMA.
// grid 512 = b*32 + t-chunk(64); block 256 = 4 waves x 16 t; all 1024 o.
// ---------------------------------------------------------------------------
__global__ __launch_bounds__(256) void gather_kernel(
    const float* __restrict__ cb, const half8* __restrict__ wf,
    const int* __restrict__ codes_i, float* __restrict__ out,
    float* __restrict__ loss_acc) {
  int tid = threadIdx.x;
  int w = tid >> 6, l = tid & 63;
  int n = l & 15, q = l >> 4;
  int blk = blockIdx.x;
  int b = blk >> 5, t0 = (blk & 31) * 64;
  int t = t0 + w * 16 + n;

  int code = codes_i[b * TT + t];
  const float* cbr = cb + (size_t)code * CC;
  float qv[2][8];
#pragma unroll
  for (int ks = 0; ks < 2; ++ks) {
    float4 a = *(const float4*)&cbr[ks * 32 + q * 8];
    float4 c4 = *(const float4*)&cbr[ks * 32 + q * 8 + 4];
    qv[ks][0] = a.x; qv[ks][1] = a.y; qv[ks][2] = a.z; qv[ks][3] = a.w;
    qv[ks][4] = c4.x; qv[ks][5] = c4.y; qv[ks][6] = c4.z; qv[ks][7] = c4.w;
  }

  // quantized_proj + loss
  float ls = 0.f;
#pragma unroll
  for (int ks = 0; ks < 2; ++ks)
#pragma unroll
    for (int j = 0; j < 8; ++j) {
      int c = ks * 32 + q * 8 + j;
      size_t g = (size_t)(b * CC + c) * TT + t;
      float qq = qv[ks][j];
      out[O_QPROJ + g] = qq;
      float d = out[O_XPROJ + g] - qq;
      ls = fmaf(d, d, ls);
    }
  for (int off = 32; off; off >>= 1) ls += __shfl_down(ls, off);
  if (l == 0) atomicAdd(loss_acc, ls);

  // B-frags
  half8 qh[2], ql[2];
#pragma unroll
  for (int ks = 0; ks < 2; ++ks) {
#pragma unroll
    for (int j = 0; j < 8; ++j) {
      qh[ks][j] = (_Float16)qv[ks][j];
      ql[ks][j] = (_Float16)(qv[ks][j] - (float)qh[ks][j]);
    }
  }

  // W_out GEMM: 64 o-tiles, K=64 (2 ksteps), 3 split terms
  for (int ot = 0; ot < 64; ++ot) {
    half8 wh0 = wf[(ot * 2 + 0) * 64 + l];
    half8 wh1 = wf[(ot * 2 + 1) * 64 + l];
    half8 wl0 = wf[8192 + (ot * 2 + 0) * 64 + l];
    half8 wl1 = wf[8192 + (ot * 2 + 1) * 64 + l];
    f32x4 acc = (f32x4){0.f, 0.f, 0.f, 0.f};
    acc = __builtin_amdgcn_mfma_f32_16x16x32_f16(wh0, qh[0], acc, 0, 0, 0);
    acc = __builtin_amdgcn_mfma_f32_16x16x32_f16(wh1, qh[1], acc, 0, 0, 0);
    acc = __builtin_amdgcn_mfma_f32_16x16x32_f16(wh0, ql[0], acc, 0, 0, 0);
    acc = __builtin_amdgcn_mfma_f32_16x16x32_f16(wh1, ql[1], acc, 0, 0, 0);
    acc = __builtin_amdgcn_mfma_f32_16x16x32_f16(wl0, qh[0], acc, 0, 0, 0);
    acc = __builtin_amdgcn_mfma_f32_16x16x32_f16(wl1, qh[1], acc, 0, 0, 0);
#pragma unroll
    for (int r = 0; r < 4; ++r)
      out[O_QUANT + (size_t)(b * CE + ot * 16 + q * 4 + r) * TT + t] = acc[r];
  }
}

// ---------------------------------------------------------------------------
// Kernel 6: finalize losses
// ---------------------------------------------------------------------------
__global__ void finalize_kernel(const float* __restrict__ ws, float* __restrict__ out) {
  if (threadIdx.x == 0 && blockIdx.x == 0) {
    float l = ws[W_LOSS] / 2097152.f;  // B*CC*T
    out[O_CBL] = l;
    out[O_CML] = l;
  }
}

extern "C" void kernel_launch(void* const* d_in, const int* in_sizes, int n_in,
                              void* d_out, int out_size, void* d_ws, size_t ws_size,
                              hipStream_t stream) {
  const float* x     = (const float*)d_in[0];
  const float* v_in  = (const float*)d_in[1];
  const float* g_in  = (const float*)d_in[2];
  const float* v_out = (const float*)d_in[3];
  const float* g_out = (const float*)d_in[4];
  const float* cb    = (const float*)d_in[5];
  float* out = (float*)d_out;
  float* ws  = (float*)d_ws;
  int* codes_i = (int*)(ws + W_CODES);

  prep_kernel<<<64 + 1024 + 4096, 64, 0, stream>>>(v_in, g_in, v_out, g_out, cb, ws);
  proj_in_kernel<<<512, 256, 0, stream>>>(x, (const half8*)(ws + W_WINF),
                                          out, ws + W_NORMS);
  dist_kernel<<<512, 256, 0, stream>>>(out + O_XPROJ, ws + W_NORMS,
                                       ws + W_CBSQ, (const uint4*)(ws + W_BF),
                                       ws + W_PB, (int*)(ws + W_PIDX));
  merge_kernel<<<128, 256, 0, stream>>>(ws + W_PB, (const int*)(ws + W_PIDX),
                                        out, codes_i);
  gather_kernel<<<512, 256, 0, stream>>>(cb, (const half8*)(ws + W_WOUTF),
                                         codes_i, out, ws + W_LOSS);
  finalize_kernel<<<1, 64, 0, stream>>>(ws, out);
}